// Round 12
// baseline (70.040 us; speedup 1.0000x reference)
//
#include <hip/hip_runtime.h>
#include <hip/hip_bf16.h>

typedef unsigned short u16;
typedef unsigned int u32;
typedef __attribute__((ext_vector_type(4))) float f32x4;
typedef __attribute__((ext_vector_type(8))) short bf16x8;
typedef __attribute__((ext_vector_type(4))) unsigned int u32x4;
typedef __attribute__((ext_vector_type(8))) unsigned short u16x8;

#define DEV static __device__ __forceinline__

// Shapes: B=4 L=5 HW=1024 C=256 M=8 D=32 T=2 R=4 INNER=256
// Activations: 8-col-chunked  X[bl][chunk=c/8][row][8] (bf16)
// P cols (1280): [0:256) k | [256+tj*256) q2[tj] | [768+ti*256) v2[ti]
// Weights chunked along K: Wbig[t][kchunk][o][8], awb[t][kchunk][o][8]

DEV u16 f2b(float f) {  // RNE f32->bf16
  unsigned u = __float_as_uint(f);
  u = (u + 0x7FFFu + ((u >> 16) & 1u)) >> 16;
  return (u16)u;
}

// ---------------- fused prep: conv_x | mask-bits | fold weights ----------------
// grid: [0,320) conv_x  [320,336) mask-bits  [336,3408) prep_w
__global__ __launch_bounds__(256) void prep_all_kernel(
    const float* __restrict__ x, const float* __restrict__ mask,
    const float* __restrict__ q_w, const float* __restrict__ q_b,
    const float* __restrict__ k_w, const float* __restrict__ k_b,
    const float* __restrict__ v_w, const float* __restrict__ v_b,
    const float* __restrict__ a_w,
    const float* __restrict__ r_att, const float* __restrict__ r_msg,
    u16* __restrict__ xbC, u32* __restrict__ maskB,
    u16* __restrict__ WbigC, float* __restrict__ Bbig, u16* __restrict__ awbC) {
  __shared__ u16 s[64 * 256];  // 32KB (used by conv_x branch only)
  const int bid = blockIdx.x, tid = threadIdx.x;
  if (bid < 320) {
    // ---- x f32 -> bf16 chunked (LDS transpose), XOR-swizzled slots ----
    const int bl = bid >> 4, rg = bid & 15;
    const float* xp = x + ((size_t)bl * 1024 + rg * 64) * 256;
    #pragma unroll
    for (int it = 0; it < 8; it++) {
      const int idx = (it * 256 + tid) * 8;
      const int row = idx >> 8;
      const int ch0 = (idx >> 3) & 31;
      f32x4 v0 = *(const f32x4*)(xp + idx);
      f32x4 v1 = *(const f32x4*)(xp + idx + 4);
      u16x8 o;
      o[0] = f2b(v0[0]); o[1] = f2b(v0[1]); o[2] = f2b(v0[2]); o[3] = f2b(v0[3]);
      o[4] = f2b(v1[0]); o[5] = f2b(v1[1]); o[6] = f2b(v1[2]); o[7] = f2b(v1[3]);
      *(u16x8*)&s[row * 256 + ((ch0 ^ (row & 31)) * 8)] = o;
    }
    __syncthreads();
    const int r = tid & 63;
    #pragma unroll
    for (int cc = 0; cc < 8; cc++) {
      const int ch = cc * 4 + (tid >> 6);
      u16x8 v = *(const u16x8*)&s[r * 256 + ((ch ^ (r & 31)) * 8)];
      *(u16x8*)(xbC + (((size_t)bl * 32 + ch) * 1024 + rg * 64 + r) * 8) = v;
    }
  } else if (bid < 336) {
    // ---- mask -> 25-bit "is-zero" bitmask per (b,r) ----
    const int i2 = (bid - 320) * 256 + tid;  // 0..4095
    const int b = i2 >> 10, r = i2 & 1023;
    const float* mp = mask + ((size_t)b * 1024 + r) * 25;
    u32 bits = 0;
    #pragma unroll
    for (int k = 0; k < 25; k++) bits |= (mp[k] == 0.f ? 1u : 0u) << k;
    maskB[i2] = bits;
  } else {
    // ---- fold relation mats into projection weights (chunked out) ----
    int idx = (bid - 336) * 256 + tid;
    const int NW = 2 * 1280 * 256;
    if (idx < NW) {
      int t = idx / (1280 * 256);
      int o = (idx / 256) % 1280;
      int c = idx & 255;
      float val;
      if (o < 256) {
        val = k_w[(size_t)(t * 256 + o) * 256 + c];
        if (c == 0) Bbig[t * 1280 + o] = k_b[t * 256 + o];
      } else if (o < 768) {
        int sec = o - 256, tj = sec >> 8, q_ = sec & 255;
        int mh = q_ >> 5, qq = q_ & 31;
        const float* W = r_att + (size_t)((t * 2 + tj) * 8 + mh) * 1024;
        const float* qwc = q_w + (size_t)(t * 256 + mh * 32) * 256 + c;
        float sacc = 0.f;
        for (int p = 0; p < 32; p++) sacc += qwc[p * 256] * W[p * 32 + qq];
        val = sacc;
        if (c == 0) {
          float sb = 0.f;
          const float* qb = q_b + t * 256 + mh * 32;
          for (int p = 0; p < 32; p++) sb += qb[p] * W[p * 32 + qq];
          Bbig[t * 1280 + o] = sb;
        }
      } else {
        int sec = o - 768, ti = sec >> 8, c_ = sec & 255;
        int mh = c_ >> 5, cc = c_ & 31;
        const float* W = r_msg + (size_t)((ti * 2 + t) * 8 + mh) * 1024;
        const float* vwc = v_w + (size_t)(t * 256 + mh * 32) * 256 + c;
        float sacc = 0.f;
        for (int p = 0; p < 32; p++) sacc += vwc[p * 256] * W[p * 32 + cc];
        val = sacc;
        if (c == 0) {
          float sb = 0.f;
          const float* vb = v_b + t * 256 + mh * 32;
          for (int p = 0; p < 32; p++) sb += vb[p] * W[p * 32 + cc];
          Bbig[t * 1280 + o] = sb;
        }
      }
      WbigC[(((size_t)t * 32 + (c >> 3)) * 1280 + o) * 8 + (c & 7)] = f2b(val);
    } else {
      int k = idx - NW;
      if (k < 2 * 256 * 256) {
        int t2 = k >> 16, o2 = (k >> 8) & 255, c2 = k & 255;
        awbC[(((size_t)t2 * 32 + (c2 >> 3)) * 256 + o2) * 8 + (c2 & 7)] = f2b(a_w[k]);
      }
    }
  }
}

DEV void gld16(const u16* g, u16* l) {
  __builtin_amdgcn_global_load_lds((const __attribute__((address_space(1))) void*)g,
                                   (__attribute__((address_space(3))) void*)l, 16, 0, 0);
}

// ---------------- bf16 GEMM: (1024 x 256) x (256 x NTOT) per (b,l) ----------------
// 128x128 tile, 4 waves, acc[4][4]; dbuf staged, FULL vmcnt(0) drain per iter
// (counted vmcnt retired: raced under codegen pressure in R8/R9/R11).
// OUT_BF16: shared-LDS-bounce vectorized epilogue (R10-verified).
// else: wave-private two-pass f32 bounce epilogue, f32x4 stores (race-free:
//       no cross-wave LDS sharing; DS pipe is in-order per wave).
template <int NTOT, bool OUT_BF16, bool OUT_CHUNKED>
__global__ __launch_bounds__(256) void gemm_kernel(
    const u16* __restrict__ A, const u16* __restrict__ Wb,
    const float* __restrict__ bias, const float* __restrict__ pe,
    void* __restrict__ Out) {
  __shared__ u16 smem[16384];  // 32 KB: k-loop dbuf; epilogue bounce reuses it
  u16* a_lds = smem;           // buf*4096
  u16* b_lds = smem + 8192;
  constexpr int NCT = NTOT / 128;
  const int lin = blockIdx.x;
  const int xcd = lin & 7;
  const int jj = lin >> 3;
  const int ct = jj % NCT;
  const int pl = jj / NCT;           // 0..19
  const int pair = xcd * 20 + pl;    // 0..159
  const int bl = pair >> 3, rt = pair & 7;

  const int t = (int)pe[(size_t)bl * 3072 + 2];
  const int tid = threadIdx.x, w = tid >> 6, lane = tid & 63;
  const int wm = w >> 1, wn = w & 1;  // wave quadrant (64x64 each)
  const u16* Ab = A + (size_t)bl * 32 * 1024 * 8;
  const u16* Bb = Wb + (size_t)t * 32 * NTOT * 8;
  f32x4 acc[4][4] = {};
  const int r16 = lane & 15, kg8 = lane >> 4;

  // hoist bias loads before the loop (keeps loop window clean; cheap anyway)
  float bv4[4];
  #pragma unroll
  for (int ni = 0; ni < 4; ni++)
    bv4[ni] = bias[t * NTOT + ct * 128 + wn * 64 + ni * 16 + r16];
  asm volatile("" :: "v"(bv4[0]), "v"(bv4[1]), "v"(bv4[2]), "v"(bv4[3]));
  asm volatile("s_waitcnt vmcnt(0)" ::: "memory");

  auto STAGE = [&](int kk, int buf) {
    const int c = kk * 4 + w;  // this wave's k-chunk
    #pragma unroll
    for (int h = 0; h < 2; h++) {
      gld16(Ab + ((size_t)c * 1024 + rt * 128 + h * 64 + lane) * 8,
            a_lds + buf * 4096 + (w * 128 + h * 64) * 8);
      gld16(Bb + ((size_t)c * NTOT + ct * 128 + h * 64 + lane) * 8,
            b_lds + buf * 4096 + (w * 128 + h * 64) * 8);
    }
  };

  STAGE(0, 0);
  #pragma unroll
  for (int kk = 0; kk < 8; kk++) {
    const int cur = kk & 1;
    if (kk < 7) STAGE(kk + 1, cur ^ 1);
    asm volatile("s_waitcnt vmcnt(0)" ::: "memory");  // full drain: count-proof
    __builtin_amdgcn_s_barrier();
    bf16x8 af[4], bfr[4];
    #pragma unroll
    for (int mi = 0; mi < 4; mi++)
      af[mi] = *(const bf16x8*)&a_lds[cur * 4096 + (kg8 * 128 + wm * 64 + mi * 16 + r16) * 8];
    #pragma unroll
    for (int ni = 0; ni < 4; ni++)
      bfr[ni] = *(const bf16x8*)&b_lds[cur * 4096 + (kg8 * 128 + wn * 64 + ni * 16 + r16) * 8];
    #pragma unroll
    for (int mi = 0; mi < 4; mi++)
      #pragma unroll
      for (int ni = 0; ni < 4; ni++)
        acc[mi][ni] =
            __builtin_amdgcn_mfma_f32_16x16x32_bf16(af[mi], bfr[ni], acc[mi][ni], 0, 0, 0);
    __builtin_amdgcn_s_barrier();  // all reads of buf done before next overwrite
  }
  __syncthreads();  // k-loop LDS retired; smem reused below

  // MFMA D frag: row=(lane>>4)*4+rg, col=lane&15 (m89-verified)
  if constexpr (OUT_BF16) {
    // shared bounce: [128 rows][16 chunks (XOR-swz by row&7)][8] u16  (R10-verified)
    #pragma unroll
    for (int mi = 0; mi < 4; mi++)
      #pragma unroll
      for (int ni = 0; ni < 4; ni++) {
        const int col_t = wn * 64 + ni * 16 + r16;
        const int ch = col_t >> 3, e = col_t & 7;
        #pragma unroll
        for (int rg = 0; rg < 4; rg++) {
          const int row_t = wm * 64 + mi * 16 + kg8 * 4 + rg;
          smem[row_t * 128 + ((ch ^ (row_t & 7)) << 3) + e] = f2b(acc[mi][ni][rg] + bv4[ni]);
        }
      }
    __syncthreads();
    u16* OutP = (u16*)Out;
    #pragma unroll
    for (int it = 0; it < 8; it++) {
      const int unit = it * 256 + tid;             // 0..2047
      const int row = unit & 127, ch = unit >> 7;  // ch 0..15
      u16x8 v = *(const u16x8*)&smem[row * 128 + ((ch ^ (row & 7)) << 3)];
      *(u16x8*)(OutP + (((size_t)bl * (NTOT / 8) + ct * 16 + ch) * 1024 + rt * 128 + row) * 8) = v;
    }
  } else {
    // wave-private two-pass f32 bounce: each wave stages its 32x64 f32 half-subtile
    // into its own 8 KB slice (4x8KB = 32KB; no cross-wave LDS sharing -> race-free).
    float* OutF = (float*)Out;
    float* epf = (float*)(smem) + w * 2048;  // wave-private 8 KB (2048 f32)
    #pragma unroll
    for (int ph = 0; ph < 2; ph++) {
      if (ph) asm volatile("s_waitcnt lgkmcnt(0)" ::: "memory");  // intra-wave WAR
      #pragma unroll
      for (int m2 = 0; m2 < 2; m2++) {
        const int mi = ph * 2 + m2;
        #pragma unroll
        for (int ni = 0; ni < 4; ni++) {
          const int lcol = ni * 16 + r16;
          #pragma unroll
          for (int rg = 0; rg < 4; rg++) {
            const int lrow = m2 * 16 + kg8 * 4 + rg;  // 0..31
            epf[lrow * 64 + (lcol ^ ((lrow & 7) << 2))] = acc[mi][ni][rg] + bv4[ni];
          }
        }
      }
      asm volatile("s_waitcnt lgkmcnt(0)" ::: "memory");
      #pragma unroll
      for (int u = 0; u < 8; u++) {
        const int row = u * 4 + kg8;   // 0..31
        const int c4 = r16 * 4;        // 0..60
        f32x4 v = *(const f32x4*)&epf[row * 64 + (c4 ^ ((row & 7) << 2))];
        *(f32x4*)(OutF + ((size_t)bl * 1024 + rt * 128 + wm * 64 + ph * 32 + row) * NTOT +
                  ct * 128 + wn * 64 + c4) = v;
      }
    }
  }
}

// ---------------- attention: 4 waves/block; wave = 16 rows x 4 chunk-lanes ----------------
DEV u32x4 ld16(const u16* p) { return *(const u32x4*)p; }
DEV void cvt8(u32x4 v, float* f) {
  #pragma unroll
  for (int e = 0; e < 4; e++) {
    f[2 * e]     = __uint_as_float(v[e] << 16);
    f[2 * e + 1] = __uint_as_float(v[e] & 0xffff0000u);
  }
}

__global__ __launch_bounds__(256) void attn_kernel(
    const u16* __restrict__ P, const u32* __restrict__ maskB,
    const float* __restrict__ pe, u16* __restrict__ AO) {
  const int m = blockIdx.y, b = blockIdx.z;
  const int tid = threadIdx.x, w = tid >> 6, lane = tid & 63;
  const int rt = blockIdx.x * 4 + w;
  const int r = rt * 16 + (lane & 15);
  const int ch = lane >> 4;
  const int cbk = m * 4 + ch;
  int tl[5];
  #pragma unroll
  for (int l = 0; l < 5; l++) tl[l] = (int)pe[(size_t)(b * 5 + l) * 3072 + 2];
  const float scale = 0.17677669529663687f;  // 1/sqrt(32)

  // ---- issue QK loads + mask bits (one latency phase) ----
  const u32 mb = maskB[b * 1024 + r];
  u32x4 kv[5], qav[5], qbv[5];
  #pragma unroll
  for (int j = 0; j < 5; j++)
    kv[j] = ld16(P + (((size_t)(b * 5 + j) * 160 + cbk) * 1024 + r) * 8);
  #pragma unroll
  for (int i = 0; i < 5; i++) {
    qav[i] = ld16(P + (((size_t)(b * 5 + i) * 160 + 32 + cbk) * 1024 + r) * 8);
    qbv[i] = ld16(P + (((size_t)(b * 5 + i) * 160 + 64 + cbk) * 1024 + r) * 8);
  }

  float kf[5][8];
  #pragma unroll
  for (int j = 0; j < 5; j++) cvt8(kv[j], kf[j]);

  float att[5][5];
  #pragma unroll
  for (int i = 0; i < 5; i++) {
    float qa[8], qb[8];
    cvt8(qav[i], qa);
    cvt8(qbv[i], qb);
    #pragma unroll
    for (int j = 0; j < 5; j++) {
      float s = 0.f;
      if (tl[j]) {
        #pragma unroll
        for (int e = 0; e < 8; e++) s += qb[e] * kf[j][e];
      } else {
        #pragma unroll
        for (int e = 0; e < 8; e++) s += qa[e] * kf[j][e];
      }
      att[i][j] = s;
    }
  }

  // ---- issue V loads NOW: latency hides under shfl-reduce + softmax ----
  u32x4 vav[5], vbv[5];
  #pragma unroll
  for (int j = 0; j < 5; j++) {
    vav[j] = ld16(P + (((size_t)(b * 5 + j) * 160 + 96 + cbk) * 1024 + r) * 8);
    vbv[j] = ld16(P + (((size_t)(b * 5 + j) * 160 + 128 + cbk) * 1024 + r) * 8);
  }

  // ---- reduce partial dots across the 4 chunk-lanes ----
  #pragma unroll
  for (int i = 0; i < 5; i++)
    #pragma unroll
    for (int j = 0; j < 5; j++) {
      float v = att[i][j];
      v += __shfl_xor(v, 16, 64);
      v += __shfl_xor(v, 32, 64);
      att[i][j] = v;
    }

  // ---- softmax (redundant across chunk groups) ----
  float p[5][5];
  #pragma unroll
  for (int i = 0; i < 5; i++) {
    float mx = -1e30f, a_[5];
    #pragma unroll
    for (int j = 0; j < 5; j++) {
      float a = att[i][j] * scale;
      if ((mb >> (i * 5 + j)) & 1) a = -1e30f;
      a_[j] = a;
      mx = fmaxf(mx, a);
    }
    float s = 0.f;
    #pragma unroll
    for (int j = 0; j < 5; j++) {
      float e = __expf(a_[j] - mx);
      p[i][j] = e;
      s += e;
    }
    const float inv = 1.f / s;
    #pragma unroll
    for (int j = 0; j < 5; j++) p[i][j] *= inv;
  }

  // ---- PV ----
  float acc[5][8] = {};
  #pragma unroll
  for (int j = 0; j < 5; j++) {
    float va[8], vb[8];
    cvt8(vav[j], va);
    cvt8(vbv[j], vb);
    #pragma unroll
    for (int i = 0; i < 5; i++) {
      const float pij = p[i][j];
      if (tl[i]) {
        #pragma unroll
        for (int e = 0; e < 8; e++) acc[i][e] += pij * vb[e];
      } else {
        #pragma unroll
        for (int e = 0; e < 8; e++) acc[i][e] += pij * va[e];
      }
    }
  }
  #pragma unroll
  for (int i = 0; i < 5; i++) {
    u16x8 o;
    #pragma unroll
    for (int e = 0; e < 8; e++) o[e] = f2b(acc[i][e]);
    *(u16x8*)(AO + (((size_t)(b * 5 + i) * 32 + cbk) * 1024 + r) * 8) = o;
  }
}

// ---------------- launch ----------------
extern "C" void kernel_launch(void* const* d_in, const int* in_sizes, int n_in,
                              void* d_out, int out_size, void* d_ws, size_t ws_size,
                              hipStream_t stream) {
  const float* x     = (const float*)d_in[0];
  const float* mask  = (const float*)d_in[1];
  const float* pe    = (const float*)d_in[2];
  const float* q_w   = (const float*)d_in[3];
  const float* q_b   = (const float*)d_in[4];
  const float* k_w   = (const float*)d_in[5];
  const float* k_b   = (const float*)d_in[6];
  const float* v_w   = (const float*)d_in[7];
  const float* v_b   = (const float*)d_in[8];
  const float* a_w   = (const float*)d_in[9];
  const float* a_b   = (const float*)d_in[10];
  const float* r_att = (const float*)d_in[11];
  const float* r_msg = (const float*)d_in[12];

  char* ws = (char*)d_ws;
  u16*   xbC   = (u16*)(ws + 0);           // 20480*256 bf16   = 10,485,760 B
  u16*   P     = (u16*)(ws + 10485760);    // 20480*1280 bf16  = 52,428,800 B
  u16*   AO    = (u16*)(ws + 62914560);    // 20480*256 bf16   = 10,485,760 B
  u16*   WbigC = (u16*)(ws + 73400320);    // 2*1280*256 bf16  =  1,310,720 B
  float* Bbig  = (float*)(ws + 74711040);  // 2*1280 f32       =     10,240 B
  u16*   awbC  = (u16*)(ws + 74721280);    // 2*256*256 bf16   =    262,144 B
  u32*   maskB = (u32*)(ws + 74983424);    // 4*1024 u32       =     16,384 B

  prep_all_kernel<<<dim3(3408), dim3(256), 0, stream>>>(
      x, mask, q_w, q_b, k_w, k_b, v_w, v_b, a_w, r_att, r_msg,
      xbC, maskB, WbigC, Bbig, awbC);
  gemm_kernel<1280, true, true><<<dim3(1600), dim3(256), 0, stream>>>(
      xbC, WbigC, Bbig, pe, (void*)P);
  attn_kernel<<<dim3(16, 8, 4), dim3(256), 0, stream>>>(P, maskB, pe, AO);
  gemm_kernel<256, false, false><<<dim3(320), dim3(256), 0, stream>>>(
      AO, awbC, a_b, pe, d_out);
}

// Round 13
// 67.590 us; speedup vs baseline: 1.0362x; 1.0362x over previous
//
#include <hip/hip_runtime.h>
#include <hip/hip_bf16.h>

typedef unsigned short u16;
typedef unsigned int u32;
typedef __attribute__((ext_vector_type(4))) float f32x4;
typedef __attribute__((ext_vector_type(8))) short bf16x8;
typedef __attribute__((ext_vector_type(4))) unsigned int u32x4;
typedef __attribute__((ext_vector_type(8))) unsigned short u16x8;

#define DEV static __device__ __forceinline__

// Shapes: B=4 L=5 HW=1024 C=256 M=8 D=32 T=2 R=4 INNER=256
// Activations: 8-col-chunked  X[bl][chunk=c/8][row][8] (bf16)
// P cols (1280): [0:256) k | [256+tj*256) q2[tj] | [768+ti*256) v2[ti]
// Weights chunked along K: Wbig[t][kchunk][o][8], awb[t][kchunk][o][8]

DEV u16 f2b(float f) {  // RNE f32->bf16
  unsigned u = __float_as_uint(f);
  u = (u + 0x7FFFu + ((u >> 16) & 1u)) >> 16;
  return (u16)u;
}

// ---------------- fused prep: conv_x | mask-bits | fold weights ----------------
// grid: [0,320) conv_x  [320,336) mask-bits  [336,3408) prep_w
__global__ __launch_bounds__(256) void prep_all_kernel(
    const float* __restrict__ x, const float* __restrict__ mask,
    const float* __restrict__ q_w, const float* __restrict__ q_b,
    const float* __restrict__ k_w, const float* __restrict__ k_b,
    const float* __restrict__ v_w, const float* __restrict__ v_b,
    const float* __restrict__ a_w,
    const float* __restrict__ r_att, const float* __restrict__ r_msg,
    u16* __restrict__ xbC, u32* __restrict__ maskB,
    u16* __restrict__ WbigC, float* __restrict__ Bbig, u16* __restrict__ awbC) {
  __shared__ u16 s[64 * 256];  // 32KB (used by conv_x branch only)
  const int bid = blockIdx.x, tid = threadIdx.x;
  if (bid < 320) {
    // ---- x f32 -> bf16 chunked (LDS transpose), XOR-swizzled slots ----
    const int bl = bid >> 4, rg = bid & 15;
    const float* xp = x + ((size_t)bl * 1024 + rg * 64) * 256;
    #pragma unroll
    for (int it = 0; it < 8; it++) {
      const int idx = (it * 256 + tid) * 8;
      const int row = idx >> 8;
      const int ch0 = (idx >> 3) & 31;
      f32x4 v0 = *(const f32x4*)(xp + idx);
      f32x4 v1 = *(const f32x4*)(xp + idx + 4);
      u16x8 o;
      o[0] = f2b(v0[0]); o[1] = f2b(v0[1]); o[2] = f2b(v0[2]); o[3] = f2b(v0[3]);
      o[4] = f2b(v1[0]); o[5] = f2b(v1[1]); o[6] = f2b(v1[2]); o[7] = f2b(v1[3]);
      *(u16x8*)&s[row * 256 + ((ch0 ^ (row & 31)) * 8)] = o;
    }
    __syncthreads();
    const int r = tid & 63;
    #pragma unroll
    for (int cc = 0; cc < 8; cc++) {
      const int ch = cc * 4 + (tid >> 6);
      u16x8 v = *(const u16x8*)&s[r * 256 + ((ch ^ (r & 31)) * 8)];
      *(u16x8*)(xbC + (((size_t)bl * 32 + ch) * 1024 + rg * 64 + r) * 8) = v;
    }
  } else if (bid < 336) {
    // ---- mask -> 25-bit "is-zero" bitmask per (b,r) ----
    const int i2 = (bid - 320) * 256 + tid;  // 0..4095
    const int b = i2 >> 10, r = i2 & 1023;
    const float* mp = mask + ((size_t)b * 1024 + r) * 25;
    u32 bits = 0;
    #pragma unroll
    for (int k = 0; k < 25; k++) bits |= (mp[k] == 0.f ? 1u : 0u) << k;
    maskB[i2] = bits;
  } else {
    // ---- fold relation mats into projection weights (chunked out) ----
    int idx = (bid - 336) * 256 + tid;
    const int NW = 2 * 1280 * 256;
    if (idx < NW) {
      int t = idx / (1280 * 256);
      int o = (idx / 256) % 1280;
      int c = idx & 255;
      float val;
      if (o < 256) {
        val = k_w[(size_t)(t * 256 + o) * 256 + c];
        if (c == 0) Bbig[t * 1280 + o] = k_b[t * 256 + o];
      } else if (o < 768) {
        int sec = o - 256, tj = sec >> 8, q_ = sec & 255;
        int mh = q_ >> 5, qq = q_ & 31;
        const float* W = r_att + (size_t)((t * 2 + tj) * 8 + mh) * 1024;
        const float* qwc = q_w + (size_t)(t * 256 + mh * 32) * 256 + c;
        float sacc = 0.f;
        for (int p = 0; p < 32; p++) sacc += qwc[p * 256] * W[p * 32 + qq];
        val = sacc;
        if (c == 0) {
          float sb = 0.f;
          const float* qb = q_b + t * 256 + mh * 32;
          for (int p = 0; p < 32; p++) sb += qb[p] * W[p * 32 + qq];
          Bbig[t * 1280 + o] = sb;
        }
      } else {
        int sec = o - 768, ti = sec >> 8, c_ = sec & 255;
        int mh = c_ >> 5, cc = c_ & 31;
        const float* W = r_msg + (size_t)((ti * 2 + t) * 8 + mh) * 1024;
        const float* vwc = v_w + (size_t)(t * 256 + mh * 32) * 256 + c;
        float sacc = 0.f;
        for (int p = 0; p < 32; p++) sacc += vwc[p * 256] * W[p * 32 + cc];
        val = sacc;
        if (c == 0) {
          float sb = 0.f;
          const float* vb = v_b + t * 256 + mh * 32;
          for (int p = 0; p < 32; p++) sb += vb[p] * W[p * 32 + cc];
          Bbig[t * 1280 + o] = sb;
        }
      }
      WbigC[(((size_t)t * 32 + (c >> 3)) * 1280 + o) * 8 + (c & 7)] = f2b(val);
    } else {
      int k = idx - NW;
      if (k < 2 * 256 * 256) {
        int t2 = k >> 16, o2 = (k >> 8) & 255, c2 = k & 255;
        awbC[(((size_t)t2 * 32 + (c2 >> 3)) * 256 + o2) * 8 + (c2 & 7)] = f2b(a_w[k]);
      }
    }
  }
}

// ---------------- bf16 GEMM: (1024 x 256) x (256 x NTOT) per (b,l) ----------------
// 128x128 tile, 4 waves, acc[4][4]; REGISTER-STAGED double-buffered pipeline:
// global->VGPR prefetch of tile k+1 overlaps compute of tile k; ds_write from
// regs; ONE __syncthreads per iter. Zero inline asm -> compiler-managed waits,
// race-free by construction. Epilogues: R10/R12-verified bounce paths.
template <int NTOT, bool OUT_BF16, bool OUT_CHUNKED>
__global__ __launch_bounds__(256) void gemm_kernel(
    const u16* __restrict__ A, const u16* __restrict__ Wb,
    const float* __restrict__ bias, const float* __restrict__ pe,
    void* __restrict__ Out) {
  __shared__ u16 smem[16384];  // 32 KB: k-loop dbuf; epilogue bounce reuses it
  u16* a_lds = smem;           // per buf: 4096 u16 = [4 kg][128 row][8]
  u16* b_lds = smem + 8192;
  constexpr int NCT = NTOT / 128;
  const int lin = blockIdx.x;
  const int xcd = lin & 7;
  const int jj = lin >> 3;
  const int ct = jj % NCT;
  const int pl = jj / NCT;           // 0..19
  const int pair = xcd * 20 + pl;    // 0..159
  const int bl = pair >> 3, rt = pair & 7;

  const int t = (int)pe[(size_t)bl * 3072 + 2];
  const int tid = threadIdx.x, w = tid >> 6, lane = tid & 63;
  const int wm = w >> 1, wn = w & 1;  // wave quadrant (64x64 each)
  const u16* Ab = A + (size_t)bl * 32 * 1024 * 8;
  const u16* Bb = Wb + (size_t)t * 32 * NTOT * 8;
  f32x4 acc[4][4] = {};
  const int r16 = lane & 15, kg8 = lane >> 4;

  float bv4[4];
  #pragma unroll
  for (int ni = 0; ni < 4; ni++)
    bv4[ni] = bias[t * NTOT + ct * 128 + wn * 64 + ni * 16 + r16];

  // register-staged dbuf pipeline
  u32x4 ra[2][2], rb[2][2];
  {
    const int c = w;  // tile 0 chunk for this wave
    #pragma unroll
    for (int h = 0; h < 2; h++) {
      ra[0][h] = *(const u32x4*)(Ab + ((size_t)c * 1024 + rt * 128 + h * 64 + lane) * 8);
      rb[0][h] = *(const u32x4*)(Bb + ((size_t)c * NTOT + ct * 128 + h * 64 + lane) * 8);
    }
  }
  #pragma unroll
  for (int kk = 0; kk < 8; kk++) {
    const int cs = kk & 1;  // compile-time under full unroll (rule #20 safe)
    if (kk < 7) {           // issue next-tile loads; latency hides under compute
      const int c = (kk + 1) * 4 + w;
      #pragma unroll
      for (int h = 0; h < 2; h++) {
        ra[cs ^ 1][h] = *(const u32x4*)(Ab + ((size_t)c * 1024 + rt * 128 + h * 64 + lane) * 8);
        rb[cs ^ 1][h] = *(const u32x4*)(Bb + ((size_t)c * NTOT + ct * 128 + h * 64 + lane) * 8);
      }
    }
    // write current tile to LDS (conflict-free: lane-contiguous 16B)
    #pragma unroll
    for (int h = 0; h < 2; h++) {
      *(u32x4*)&a_lds[cs * 4096 + (w * 128 + h * 64 + lane) * 8] = ra[cs][h];
      *(u32x4*)&b_lds[cs * 4096 + (w * 128 + h * 64 + lane) * 8] = rb[cs][h];
    }
    __syncthreads();  // writes of buf cs visible; prior-iter reads of cs fenced at the previous barrier
    bf16x8 af[4], bfr[4];
    #pragma unroll
    for (int mi = 0; mi < 4; mi++)
      af[mi] = *(const bf16x8*)&a_lds[cs * 4096 + (kg8 * 128 + wm * 64 + mi * 16 + r16) * 8];
    #pragma unroll
    for (int ni = 0; ni < 4; ni++)
      bfr[ni] = *(const bf16x8*)&b_lds[cs * 4096 + (kg8 * 128 + wn * 64 + ni * 16 + r16) * 8];
    #pragma unroll
    for (int mi = 0; mi < 4; mi++)
      #pragma unroll
      for (int ni = 0; ni < 4; ni++)
        acc[mi][ni] =
            __builtin_amdgcn_mfma_f32_16x16x32_bf16(af[mi], bfr[ni], acc[mi][ni], 0, 0, 0);
    // no trailing barrier: next iter writes the OTHER buffer; this buffer is
    // next rewritten at iter kk+2, after the kk+1 barrier (lgkmcnt0) fences reads
  }
  __syncthreads();  // k-loop LDS retired; smem reused below

  // MFMA D frag: row=(lane>>4)*4+rg, col=lane&15 (m89-verified)
  if constexpr (OUT_BF16) {
    // shared bounce: [128 rows][16 chunks (XOR-swz by row&7)][8] u16  (R10-verified)
    #pragma unroll
    for (int mi = 0; mi < 4; mi++)
      #pragma unroll
      for (int ni = 0; ni < 4; ni++) {
        const int col_t = wn * 64 + ni * 16 + r16;
        const int ch = col_t >> 3, e = col_t & 7;
        #pragma unroll
        for (int rg = 0; rg < 4; rg++) {
          const int row_t = wm * 64 + mi * 16 + kg8 * 4 + rg;
          smem[row_t * 128 + ((ch ^ (row_t & 7)) << 3) + e] = f2b(acc[mi][ni][rg] + bv4[ni]);
        }
      }
    __syncthreads();
    u16* OutP = (u16*)Out;
    #pragma unroll
    for (int it = 0; it < 8; it++) {
      const int unit = it * 256 + tid;             // 0..2047
      const int row = unit & 127, ch = unit >> 7;  // ch 0..15
      u16x8 v = *(const u16x8*)&smem[row * 128 + ((ch ^ (row & 7)) << 3)];
      *(u16x8*)(OutP + (((size_t)bl * (NTOT / 8) + ct * 16 + ch) * 1024 + rt * 128 + row) * 8) = v;
    }
  } else {
    // wave-private two-pass f32 bounce (R12-verified): each wave stages its
    // 32x64 f32 half-subtile in its own 8 KB slice; DS pipe in-order per wave.
    float* OutF = (float*)Out;
    float* epf = (float*)(smem) + w * 2048;  // wave-private 8 KB (2048 f32)
    #pragma unroll
    for (int ph = 0; ph < 2; ph++) {
      if (ph) __builtin_amdgcn_s_waitcnt(0 /*lgkmcnt(0) field*/), (void)0;
      if (ph) asm volatile("s_waitcnt lgkmcnt(0)" ::: "memory");  // intra-wave WAR
      #pragma unroll
      for (int m2 = 0; m2 < 2; m2++) {
        const int mi = ph * 2 + m2;
        #pragma unroll
        for (int ni = 0; ni < 4; ni++) {
          const int lcol = ni * 16 + r16;
          #pragma unroll
          for (int rg = 0; rg < 4; rg++) {
            const int lrow = m2 * 16 + kg8 * 4 + rg;  // 0..31
            epf[lrow * 64 + (lcol ^ ((lrow & 7) << 2))] = acc[mi][ni][rg] + bv4[ni];
          }
        }
      }
      asm volatile("s_waitcnt lgkmcnt(0)" ::: "memory");
      #pragma unroll
      for (int u = 0; u < 8; u++) {
        const int row = u * 4 + kg8;   // 0..31
        const int c4 = r16 * 4;        // 0..60
        f32x4 v = *(const f32x4*)&epf[row * 64 + (c4 ^ ((row & 7) << 2))];
        *(f32x4*)(OutF + ((size_t)bl * 1024 + rt * 128 + wm * 64 + ph * 32 + row) * NTOT +
                  ct * 128 + wn * 64 + c4) = v;
      }
    }
  }
}

// ---------------- attention: 4 waves/block; wave = 16 rows x 4 chunk-lanes ----------------
DEV u32x4 ld16(const u16* p) { return *(const u32x4*)p; }
DEV void cvt8(u32x4 v, float* f) {
  #pragma unroll
  for (int e = 0; e < 4; e++) {
    f[2 * e]     = __uint_as_float(v[e] << 16);
    f[2 * e + 1] = __uint_as_float(v[e] & 0xffff0000u);
  }
}

__global__ __launch_bounds__(256) void attn_kernel(
    const u16* __restrict__ P, const u32* __restrict__ maskB,
    const float* __restrict__ pe, u16* __restrict__ AO) {
  const int m = blockIdx.y, b = blockIdx.z;
  const int tid = threadIdx.x, w = tid >> 6, lane = tid & 63;
  const int rt = blockIdx.x * 4 + w;
  const int r = rt * 16 + (lane & 15);
  const int ch = lane >> 4;
  const int cbk = m * 4 + ch;
  int tl[5];
  #pragma unroll
  for (int l = 0; l < 5; l++) tl[l] = (int)pe[(size_t)(b * 5 + l) * 3072 + 2];
  const float scale = 0.17677669529663687f;  // 1/sqrt(32)

  // ---- issue QK loads + mask bits (one latency phase) ----
  const u32 mb = maskB[b * 1024 + r];
  u32x4 kv[5], qav[5], qbv[5];
  #pragma unroll
  for (int j = 0; j < 5; j++)
    kv[j] = ld16(P + (((size_t)(b * 5 + j) * 160 + cbk) * 1024 + r) * 8);
  #pragma unroll
  for (int i = 0; i < 5; i++) {
    qav[i] = ld16(P + (((size_t)(b * 5 + i) * 160 + 32 + cbk) * 1024 + r) * 8);
    qbv[i] = ld16(P + (((size_t)(b * 5 + i) * 160 + 64 + cbk) * 1024 + r) * 8);
  }

  float kf[5][8];
  #pragma unroll
  for (int j = 0; j < 5; j++) cvt8(kv[j], kf[j]);

  float att[5][5];
  #pragma unroll
  for (int i = 0; i < 5; i++) {
    float qa[8], qb[8];
    cvt8(qav[i], qa);
    cvt8(qbv[i], qb);
    #pragma unroll
    for (int j = 0; j < 5; j++) {
      float s = 0.f;
      if (tl[j]) {
        #pragma unroll
        for (int e = 0; e < 8; e++) s += qb[e] * kf[j][e];
      } else {
        #pragma unroll
        for (int e = 0; e < 8; e++) s += qa[e] * kf[j][e];
      }
      att[i][j] = s;
    }
  }

  // ---- issue V loads NOW: latency hides under shfl-reduce + softmax ----
  u32x4 vav[5], vbv[5];
  #pragma unroll
  for (int j = 0; j < 5; j++) {
    vav[j] = ld16(P + (((size_t)(b * 5 + j) * 160 + 96 + cbk) * 1024 + r) * 8);
    vbv[j] = ld16(P + (((size_t)(b * 5 + j) * 160 + 128 + cbk) * 1024 + r) * 8);
  }

  // ---- reduce partial dots across the 4 chunk-lanes ----
  #pragma unroll
  for (int i = 0; i < 5; i++)
    #pragma unroll
    for (int j = 0; j < 5; j++) {
      float v = att[i][j];
      v += __shfl_xor(v, 16, 64);
      v += __shfl_xor(v, 32, 64);
      att[i][j] = v;
    }

  // ---- softmax (redundant across chunk groups) ----
  float p[5][5];
  #pragma unroll
  for (int i = 0; i < 5; i++) {
    float mx = -1e30f, a_[5];
    #pragma unroll
    for (int j = 0; j < 5; j++) {
      float a = att[i][j] * scale;
      if ((mb >> (i * 5 + j)) & 1) a = -1e30f;
      a_[j] = a;
      mx = fmaxf(mx, a);
    }
    float s = 0.f;
    #pragma unroll
    for (int j = 0; j < 5; j++) {
      float e = __expf(a_[j] - mx);
      p[i][j] = e;
      s += e;
    }
    const float inv = 1.f / s;
    #pragma unroll
    for (int j = 0; j < 5; j++) p[i][j] *= inv;
  }

  // ---- PV ----
  float acc[5][8] = {};
  #pragma unroll
  for (int j = 0; j < 5; j++) {
    float va[8], vb[8];
    cvt8(vav[j], va);
    cvt8(vbv[j], vb);
    #pragma unroll
    for (int i = 0; i < 5; i++) {
      const float pij = p[i][j];
      if (tl[i]) {
        #pragma unroll
        for (int e = 0; e < 8; e++) acc[i][e] += pij * vb[e];
      } else {
        #pragma unroll
        for (int e = 0; e < 8; e++) acc[i][e] += pij * va[e];
      }
    }
  }
  #pragma unroll
  for (int i = 0; i < 5; i++) {
    u16x8 o;
    #pragma unroll
    for (int e = 0; e < 8; e++) o[e] = f2b(acc[i][e]);
    *(u16x8*)(AO + (((size_t)(b * 5 + i) * 32 + cbk) * 1024 + r) * 8) = o;
  }
}

// ---------------- launch ----------------
extern "C" void kernel_launch(void* const* d_in, const int* in_sizes, int n_in,
                              void* d_out, int out_size, void* d_ws, size_t ws_size,
                              hipStream_t stream) {
  const float* x     = (const float*)d_in[0];
  const float* mask  = (const float*)d_in[1];
  const float* pe    = (const float*)d_in[2];
  const float* q_w   = (const float*)d_in[3];
  const float* q_b   = (const float*)d_in[4];
  const float* k_w   = (const float*)d_in[5];
  const float* k_b   = (const float*)d_in[6];
  const float* v_w   = (const float*)d_in[7];
  const float* v_b   = (const float*)d_in[8];
  const float* a_w   = (const float*)d_in[9];
  const float* a_b   = (const float*)d_in[10];
  const float* r_att = (const float*)d_in[11];
  const float* r_msg = (const float*)d_in[12];

  char* ws = (char*)d_ws;
  u16*   xbC   = (u16*)(ws + 0);           // 20480*256 bf16   = 10,485,760 B
  u16*   P     = (u16*)(ws + 10485760);    // 20480*1280 bf16  = 52,428,800 B
  u16*   AO    = (u16*)(ws + 62914560);    // 20480*256 bf16   = 10,485,760 B
  u16*   WbigC = (u16*)(ws + 73400320);    // 2*1280*256 bf16  =  1,310,720 B
  float* Bbig  = (float*)(ws + 74711040);  // 2*1280 f32       =     10,240 B
  u16*   awbC  = (u16*)(ws + 74721280);    // 2*256*256 bf16   =    262,144 B
  u32*   maskB = (u32*)(ws + 74983424);    // 4*1024 u32       =     16,384 B

  prep_all_kernel<<<dim3(3408), dim3(256), 0, stream>>>(
      x, mask, q_w, q_b, k_w, k_b, v_w, v_b, a_w, r_att, r_msg,
      xbC, maskB, WbigC, Bbig, awbC);
  gemm_kernel<1280, true, true><<<dim3(1600), dim3(256), 0, stream>>>(
      xbC, WbigC, Bbig, pe, (void*)P);
  attn_kernel<<<dim3(16, 8, 4), dim3(256), 0, stream>>>(P, maskB, pe, AO);
  gemm_kernel<256, false, false><<<dim3(320), dim3(256), 0, stream>>>(
      AO, awbC, a_b, pe, d_out);
}

// Round 14
// 65.843 us; speedup vs baseline: 1.0637x; 1.0265x over previous
//
#include <hip/hip_runtime.h>
#include <hip/hip_bf16.h>

typedef unsigned short u16;
typedef unsigned int u32;
typedef __attribute__((ext_vector_type(4))) float f32x4;
typedef __attribute__((ext_vector_type(8))) short bf16x8;
typedef __attribute__((ext_vector_type(4))) unsigned int u32x4;
typedef __attribute__((ext_vector_type(8))) unsigned short u16x8;

#define DEV static __device__ __forceinline__

// Shapes: B=4 L=5 HW=1024 C=256 M=8 D=32 T=2 R=4 INNER=256
// Activations: 8-col-chunked  X[bl][chunk=c/8][row][8] (bf16)
// P cols (1280): [0:256) k | [256+tj*256) q2[tj] | [768+ti*256) v2[ti]
// Weights chunked along K: Wbig[t][kchunk][o][8], awb[t][kchunk][o][8]

DEV u16 f2b(float f) {  // RNE f32->bf16
  unsigned u = __float_as_uint(f);
  u = (u + 0x7FFFu + ((u >> 16) & 1u)) >> 16;
  return (u16)u;
}

// ---------------- fused prep: conv_x | mask-bits | fold weights ----------------
// grid: [0,320) conv_x  [320,336) mask-bits  [336,3408) prep_w
__global__ __launch_bounds__(256) void prep_all_kernel(
    const float* __restrict__ x, const float* __restrict__ mask,
    const float* __restrict__ q_w, const float* __restrict__ q_b,
    const float* __restrict__ k_w, const float* __restrict__ k_b,
    const float* __restrict__ v_w, const float* __restrict__ v_b,
    const float* __restrict__ a_w,
    const float* __restrict__ r_att, const float* __restrict__ r_msg,
    u16* __restrict__ xbC, u32* __restrict__ maskB,
    u16* __restrict__ WbigC, float* __restrict__ Bbig, u16* __restrict__ awbC) {
  __shared__ u16 s[64 * 256];  // 32KB (used by conv_x branch only)
  const int bid = blockIdx.x, tid = threadIdx.x;
  if (bid < 320) {
    // ---- x f32 -> bf16 chunked (LDS transpose), XOR-swizzled slots ----
    const int bl = bid >> 4, rg = bid & 15;
    const float* xp = x + ((size_t)bl * 1024 + rg * 64) * 256;
    #pragma unroll
    for (int it = 0; it < 8; it++) {
      const int idx = (it * 256 + tid) * 8;
      const int row = idx >> 8;
      const int ch0 = (idx >> 3) & 31;
      f32x4 v0 = *(const f32x4*)(xp + idx);
      f32x4 v1 = *(const f32x4*)(xp + idx + 4);
      u16x8 o;
      o[0] = f2b(v0[0]); o[1] = f2b(v0[1]); o[2] = f2b(v0[2]); o[3] = f2b(v0[3]);
      o[4] = f2b(v1[0]); o[5] = f2b(v1[1]); o[6] = f2b(v1[2]); o[7] = f2b(v1[3]);
      *(u16x8*)&s[row * 256 + ((ch0 ^ (row & 31)) * 8)] = o;
    }
    __syncthreads();
    const int r = tid & 63;
    #pragma unroll
    for (int cc = 0; cc < 8; cc++) {
      const int ch = cc * 4 + (tid >> 6);
      u16x8 v = *(const u16x8*)&s[r * 256 + ((ch ^ (r & 31)) * 8)];
      *(u16x8*)(xbC + (((size_t)bl * 32 + ch) * 1024 + rg * 64 + r) * 8) = v;
    }
  } else if (bid < 336) {
    // ---- mask -> 25-bit "is-zero" bitmask per (b,r) ----
    const int i2 = (bid - 320) * 256 + tid;  // 0..4095
    const int b = i2 >> 10, r = i2 & 1023;
    const float* mp = mask + ((size_t)b * 1024 + r) * 25;
    u32 bits = 0;
    #pragma unroll
    for (int k = 0; k < 25; k++) bits |= (mp[k] == 0.f ? 1u : 0u) << k;
    maskB[i2] = bits;
  } else {
    // ---- fold relation mats into projection weights (chunked out) ----
    int idx = (bid - 336) * 256 + tid;
    const int NW = 2 * 1280 * 256;
    if (idx < NW) {
      int t = idx / (1280 * 256);
      int o = (idx / 256) % 1280;
      int c = idx & 255;
      float val;
      if (o < 256) {
        val = k_w[(size_t)(t * 256 + o) * 256 + c];
        if (c == 0) Bbig[t * 1280 + o] = k_b[t * 256 + o];
      } else if (o < 768) {
        int sec = o - 256, tj = sec >> 8, q_ = sec & 255;
        int mh = q_ >> 5, qq = q_ & 31;
        const float* W = r_att + (size_t)((t * 2 + tj) * 8 + mh) * 1024;
        const float* qwc = q_w + (size_t)(t * 256 + mh * 32) * 256 + c;
        float sacc = 0.f;
        for (int p = 0; p < 32; p++) sacc += qwc[p * 256] * W[p * 32 + qq];
        val = sacc;
        if (c == 0) {
          float sb = 0.f;
          const float* qb = q_b + t * 256 + mh * 32;
          for (int p = 0; p < 32; p++) sb += qb[p] * W[p * 32 + qq];
          Bbig[t * 1280 + o] = sb;
        }
      } else {
        int sec = o - 768, ti = sec >> 8, c_ = sec & 255;
        int mh = c_ >> 5, cc = c_ & 31;
        const float* W = r_msg + (size_t)((ti * 2 + t) * 8 + mh) * 1024;
        const float* vwc = v_w + (size_t)(t * 256 + mh * 32) * 256 + c;
        float sacc = 0.f;
        for (int p = 0; p < 32; p++) sacc += vwc[p * 256] * W[p * 32 + cc];
        val = sacc;
        if (c == 0) {
          float sb = 0.f;
          const float* vb = v_b + t * 256 + mh * 32;
          for (int p = 0; p < 32; p++) sb += vb[p] * W[p * 32 + cc];
          Bbig[t * 1280 + o] = sb;
        }
      }
      WbigC[(((size_t)t * 32 + (c >> 3)) * 1280 + o) * 8 + (c & 7)] = f2b(val);
    } else {
      int k = idx - NW;
      if (k < 2 * 256 * 256) {
        int t2 = k >> 16, o2 = (k >> 8) & 255, c2 = k & 255;
        awbC[(((size_t)t2 * 32 + (c2 >> 3)) * 256 + o2) * 8 + (c2 & 7)] = f2b(a_w[k]);
      }
    }
  }
}

// ---------------- bf16 GEMM: (1024 x 256) x (256 x NTOT) per (b,l) ----------------
// 128x128 tile, 4 waves, acc[4][4]; register-staged pipeline with 2-ITER-DEEP
// prefetch (same 2 reg slots as R13, but loads issued 2 compute phases before
// their ds_write consumes them -> ~600cy latency cover). One __syncthreads/iter.
// Zero inline asm in the k-loop -> compiler-managed waits, race-free.
// Epilogues: R10/R12-verified bounce paths.
template <int NTOT, bool OUT_BF16, bool OUT_CHUNKED>
__global__ __launch_bounds__(256) void gemm_kernel(
    const u16* __restrict__ A, const u16* __restrict__ Wb,
    const float* __restrict__ bias, const float* __restrict__ pe,
    void* __restrict__ Out) {
  __shared__ u16 smem[16384];  // 32 KB: k-loop dbuf; epilogue bounce reuses it
  u16* a_lds = smem;           // per buf: 4096 u16 = [4 kg][128 row][8]
  u16* b_lds = smem + 8192;
  constexpr int NCT = NTOT / 128;
  const int lin = blockIdx.x;
  const int xcd = lin & 7;
  const int jj = lin >> 3;
  const int ct = jj % NCT;
  const int pl = jj / NCT;           // 0..19
  const int pair = xcd * 20 + pl;    // 0..159
  const int bl = pair >> 3, rt = pair & 7;

  const int t = (int)pe[(size_t)bl * 3072 + 2];
  const int tid = threadIdx.x, w = tid >> 6, lane = tid & 63;
  const int wm = w >> 1, wn = w & 1;  // wave quadrant (64x64 each)
  const u16* Ab = A + (size_t)bl * 32 * 1024 * 8;
  const u16* Bb = Wb + (size_t)t * 32 * NTOT * 8;
  f32x4 acc[4][4] = {};
  const int r16 = lane & 15, kg8 = lane >> 4;

  float bv4[4];
  #pragma unroll
  for (int ni = 0; ni < 4; ni++)
    bv4[ni] = bias[t * NTOT + ct * 128 + wn * 64 + ni * 16 + r16];

  // register-staged dbuf pipeline, 2-deep prefetch
  u32x4 ra[2][2], rb[2][2];
  #pragma unroll
  for (int pp = 0; pp < 2; pp++) {  // preload tiles 0 and 1
    const int c = pp * 4 + w;
    #pragma unroll
    for (int h = 0; h < 2; h++) {
      ra[pp][h] = *(const u32x4*)(Ab + ((size_t)c * 1024 + rt * 128 + h * 64 + lane) * 8);
      rb[pp][h] = *(const u32x4*)(Bb + ((size_t)c * NTOT + ct * 128 + h * 64 + lane) * 8);
    }
  }
  #pragma unroll
  for (int kk = 0; kk < 8; kk++) {
    const int cs = kk & 1;  // compile-time under full unroll (rule #20 safe)
    // write tile kk to LDS from its slot (vmcnt waits only this slot's loads,
    // issued 2 iters ago -> latency fully covered)
    #pragma unroll
    for (int h = 0; h < 2; h++) {
      *(u32x4*)&a_lds[cs * 4096 + (w * 128 + h * 64 + lane) * 8] = ra[cs][h];
      *(u32x4*)&b_lds[cs * 4096 + (w * 128 + h * 64 + lane) * 8] = rb[cs][h];
    }
    if (kk < 6) {  // refill the just-freed slot with tile kk+2 (WAR via issue order)
      const int c = (kk + 2) * 4 + w;
      #pragma unroll
      for (int h = 0; h < 2; h++) {
        ra[cs][h] = *(const u32x4*)(Ab + ((size_t)c * 1024 + rt * 128 + h * 64 + lane) * 8);
        rb[cs][h] = *(const u32x4*)(Bb + ((size_t)c * NTOT + ct * 128 + h * 64 + lane) * 8);
      }
    }
    __syncthreads();  // writes of buf cs visible; prior reads of cs fenced at the previous barrier
    bf16x8 af[4], bfr[4];
    #pragma unroll
    for (int mi = 0; mi < 4; mi++)
      af[mi] = *(const bf16x8*)&a_lds[cs * 4096 + (kg8 * 128 + wm * 64 + mi * 16 + r16) * 8];
    #pragma unroll
    for (int ni = 0; ni < 4; ni++)
      bfr[ni] = *(const bf16x8*)&b_lds[cs * 4096 + (kg8 * 128 + wn * 64 + ni * 16 + r16) * 8];
    #pragma unroll
    for (int mi = 0; mi < 4; mi++)
      #pragma unroll
      for (int ni = 0; ni < 4; ni++)
        acc[mi][ni] =
            __builtin_amdgcn_mfma_f32_16x16x32_bf16(af[mi], bfr[ni], acc[mi][ni], 0, 0, 0);
    // no trailing barrier: next iter writes the OTHER buffer; this buffer is
    // next rewritten at iter kk+2, after the kk+1 barrier (lgkmcnt0) fences reads
  }
  __syncthreads();  // k-loop LDS retired; smem reused below

  // MFMA D frag: row=(lane>>4)*4+rg, col=lane&15 (m89-verified)
  if constexpr (OUT_BF16) {
    // shared bounce: [128 rows][16 chunks (XOR-swz by row&7)][8] u16  (R10-verified)
    #pragma unroll
    for (int mi = 0; mi < 4; mi++)
      #pragma unroll
      for (int ni = 0; ni < 4; ni++) {
        const int col_t = wn * 64 + ni * 16 + r16;
        const int ch = col_t >> 3, e = col_t & 7;
        #pragma unroll
        for (int rg = 0; rg < 4; rg++) {
          const int row_t = wm * 64 + mi * 16 + kg8 * 4 + rg;
          smem[row_t * 128 + ((ch ^ (row_t & 7)) << 3) + e] = f2b(acc[mi][ni][rg] + bv4[ni]);
        }
      }
    __syncthreads();
    u16* OutP = (u16*)Out;
    #pragma unroll
    for (int it = 0; it < 8; it++) {
      const int unit = it * 256 + tid;             // 0..2047
      const int row = unit & 127, ch = unit >> 7;  // ch 0..15
      u16x8 v = *(const u16x8*)&smem[row * 128 + ((ch ^ (row & 7)) << 3)];
      *(u16x8*)(OutP + (((size_t)bl * (NTOT / 8) + ct * 16 + ch) * 1024 + rt * 128 + row) * 8) = v;
    }
  } else {
    // wave-private two-pass f32 bounce (R12-verified): each wave stages its
    // 32x64 f32 half-subtile in its own 8 KB slice; DS pipe in-order per wave.
    float* OutF = (float*)Out;
    float* epf = (float*)(smem) + w * 2048;  // wave-private 8 KB (2048 f32)
    #pragma unroll
    for (int ph = 0; ph < 2; ph++) {
      if (ph) asm volatile("s_waitcnt lgkmcnt(0)" ::: "memory");  // intra-wave WAR
      #pragma unroll
      for (int m2 = 0; m2 < 2; m2++) {
        const int mi = ph * 2 + m2;
        #pragma unroll
        for (int ni = 0; ni < 4; ni++) {
          const int lcol = ni * 16 + r16;
          #pragma unroll
          for (int rg = 0; rg < 4; rg++) {
            const int lrow = m2 * 16 + kg8 * 4 + rg;  // 0..31
            epf[lrow * 64 + (lcol ^ ((lrow & 7) << 2))] = acc[mi][ni][rg] + bv4[ni];
          }
        }
      }
      asm volatile("s_waitcnt lgkmcnt(0)" ::: "memory");
      #pragma unroll
      for (int u = 0; u < 8; u++) {
        const int row = u * 4 + kg8;   // 0..31
        const int c4 = r16 * 4;        // 0..60
        f32x4 v = *(const f32x4*)&epf[row * 64 + (c4 ^ ((row & 7) << 2))];
        *(f32x4*)(OutF + ((size_t)bl * 1024 + rt * 128 + wm * 64 + ph * 32 + row) * NTOT +
                  ct * 128 + wn * 64 + c4) = v;
      }
    }
  }
}

// ---------------- attention: 4 waves/block; wave = 16 rows x 4 chunk-lanes ----------------
DEV u32x4 ld16(const u16* p) { return *(const u32x4*)p; }
DEV void cvt8(u32x4 v, float* f) {
  #pragma unroll
  for (int e = 0; e < 4; e++) {
    f[2 * e]     = __uint_as_float(v[e] << 16);
    f[2 * e + 1] = __uint_as_float(v[e] & 0xffff0000u);
  }
}

__global__ __launch_bounds__(256) void attn_kernel(
    const u16* __restrict__ P, const u32* __restrict__ maskB,
    const float* __restrict__ pe, u16* __restrict__ AO) {
  const int m = blockIdx.y, b = blockIdx.z;
  const int tid = threadIdx.x, w = tid >> 6, lane = tid & 63;
  const int rt = blockIdx.x * 4 + w;
  const int r = rt * 16 + (lane & 15);
  const int ch = lane >> 4;
  const int cbk = m * 4 + ch;
  int tl[5];
  #pragma unroll
  for (int l = 0; l < 5; l++) tl[l] = (int)pe[(size_t)(b * 5 + l) * 3072 + 2];
  const float scale = 0.17677669529663687f;  // 1/sqrt(32)

  // ---- issue QK loads + mask bits (one latency phase) ----
  const u32 mb = maskB[b * 1024 + r];
  u32x4 kv[5], qav[5], qbv[5];
  #pragma unroll
  for (int j = 0; j < 5; j++)
    kv[j] = ld16(P + (((size_t)(b * 5 + j) * 160 + cbk) * 1024 + r) * 8);
  #pragma unroll
  for (int i = 0; i < 5; i++) {
    qav[i] = ld16(P + (((size_t)(b * 5 + i) * 160 + 32 + cbk) * 1024 + r) * 8);
    qbv[i] = ld16(P + (((size_t)(b * 5 + i) * 160 + 64 + cbk) * 1024 + r) * 8);
  }

  float kf[5][8];
  #pragma unroll
  for (int j = 0; j < 5; j++) cvt8(kv[j], kf[j]);

  float att[5][5];
  #pragma unroll
  for (int i = 0; i < 5; i++) {
    float qa[8], qb[8];
    cvt8(qav[i], qa);
    cvt8(qbv[i], qb);
    #pragma unroll
    for (int j = 0; j < 5; j++) {
      float s = 0.f;
      if (tl[j]) {
        #pragma unroll
        for (int e = 0; e < 8; e++) s += qb[e] * kf[j][e];
      } else {
        #pragma unroll
        for (int e = 0; e < 8; e++) s += qa[e] * kf[j][e];
      }
      att[i][j] = s;
    }
  }

  // ---- issue V loads NOW: latency hides under shfl-reduce + softmax ----
  u32x4 vav[5], vbv[5];
  #pragma unroll
  for (int j = 0; j < 5; j++) {
    vav[j] = ld16(P + (((size_t)(b * 5 + j) * 160 + 96 + cbk) * 1024 + r) * 8);
    vbv[j] = ld16(P + (((size_t)(b * 5 + j) * 160 + 128 + cbk) * 1024 + r) * 8);
  }

  // ---- reduce partial dots across the 4 chunk-lanes ----
  #pragma unroll
  for (int i = 0; i < 5; i++)
    #pragma unroll
    for (int j = 0; j < 5; j++) {
      float v = att[i][j];
      v += __shfl_xor(v, 16, 64);
      v += __shfl_xor(v, 32, 64);
      att[i][j] = v;
    }

  // ---- softmax (redundant across chunk groups) ----
  float p[5][5];
  #pragma unroll
  for (int i = 0; i < 5; i++) {
    float mx = -1e30f, a_[5];
    #pragma unroll
    for (int j = 0; j < 5; j++) {
      float a = att[i][j] * scale;
      if ((mb >> (i * 5 + j)) & 1) a = -1e30f;
      a_[j] = a;
      mx = fmaxf(mx, a);
    }
    float s = 0.f;
    #pragma unroll
    for (int j = 0; j < 5; j++) {
      float e = __expf(a_[j] - mx);
      p[i][j] = e;
      s += e;
    }
    const float inv = 1.f / s;
    #pragma unroll
    for (int j = 0; j < 5; j++) p[i][j] *= inv;
  }

  // ---- PV ----
  float acc[5][8] = {};
  #pragma unroll
  for (int j = 0; j < 5; j++) {
    float va[8], vb[8];
    cvt8(vav[j], va);
    cvt8(vbv[j], vb);
    #pragma unroll
    for (int i = 0; i < 5; i++) {
      const float pij = p[i][j];
      if (tl[i]) {
        #pragma unroll
        for (int e = 0; e < 8; e++) acc[i][e] += pij * vb[e];
      } else {
        #pragma unroll
        for (int e = 0; e < 8; e++) acc[i][e] += pij * va[e];
      }
    }
  }
  #pragma unroll
  for (int i = 0; i < 5; i++) {
    u16x8 o;
    #pragma unroll
    for (int e = 0; e < 8; e++) o[e] = f2b(acc[i][e]);
    *(u16x8*)(AO + (((size_t)(b * 5 + i) * 32 + cbk) * 1024 + r) * 8) = o;
  }
}

// ---------------- launch ----------------
extern "C" void kernel_launch(void* const* d_in, const int* in_sizes, int n_in,
                              void* d_out, int out_size, void* d_ws, size_t ws_size,
                              hipStream_t stream) {
  const float* x     = (const float*)d_in[0];
  const float* mask  = (const float*)d_in[1];
  const float* pe    = (const float*)d_in[2];
  const float* q_w   = (const float*)d_in[3];
  const float* q_b   = (const float*)d_in[4];
  const float* k_w   = (const float*)d_in[5];
  const float* k_b   = (const float*)d_in[6];
  const float* v_w   = (const float*)d_in[7];
  const float* v_b   = (const float*)d_in[8];
  const float* a_w   = (const float*)d_in[9];
  const float* a_b   = (const float*)d_in[10];
  const float* r_att = (const float*)d_in[11];
  const float* r_msg = (const float*)d_in[12];

  char* ws = (char*)d_ws;
  u16*   xbC   = (u16*)(ws + 0);           // 20480*256 bf16   = 10,485,760 B
  u16*   P     = (u16*)(ws + 10485760);    // 20480*1280 bf16  = 52,428,800 B
  u16*   AO    = (u16*)(ws + 62914560);    // 20480*256 bf16   = 10,485,760 B
  u16*   WbigC = (u16*)(ws + 73400320);    // 2*1280*256 bf16  =  1,310,720 B
  float* Bbig  = (float*)(ws + 74711040);  // 2*1280 f32       =     10,240 B
  u16*   awbC  = (u16*)(ws + 74721280);    // 2*256*256 bf16   =    262,144 B
  u32*   maskB = (u32*)(ws + 74983424);    // 4*1024 u32       =     16,384 B

  prep_all_kernel<<<dim3(3408), dim3(256), 0, stream>>>(
      x, mask, q_w, q_b, k_w, k_b, v_w, v_b, a_w, r_att, r_msg,
      xbC, maskB, WbigC, Bbig, awbC);
  gemm_kernel<1280, true, true><<<dim3(1600), dim3(256), 0, stream>>>(
      xbC, WbigC, Bbig, pe, (void*)P);
  attn_kernel<<<dim3(16, 8, 4), dim3(256), 0, stream>>>(P, maskB, pe, AO);
  gemm_kernel<256, false, false><<<dim3(320), dim3(256), 0, stream>>>(
      AO, awbC, a_b, pe, d_out);
}